// Round 10
// baseline (618.758 us; speedup 1.0000x reference)
//
#include <hip/hip_runtime.h>

#define NN 50000
#define NG 100
#define NPG 500
#define NE 800000
#define EPG 8000
#define EMBD 128
#define NL 4
#define EB_BLOCKS 3125   // 16 nodes per block
#define FB_BLOCKS 1000   // 50 rows per block
#define FB_ROWS 50

typedef __attribute__((ext_vector_type(8))) short short8v;
typedef __attribute__((ext_vector_type(4))) float float4v;
typedef __attribute__((ext_vector_type(2))) float f2;

__device__ __forceinline__ unsigned short f2bf(float v) {
  unsigned u = __float_as_uint(v);
  u += 0x7FFFu + ((u >> 16) & 1u);
  return (unsigned short)(u >> 16);
}
__device__ __forceinline__ float bf2f(unsigned short h) {
  return __uint_as_float(((unsigned)h) << 16);
}

__device__ __forceinline__ float fexp2(float x) {
#if __has_builtin(__builtin_amdgcn_exp2f)
  return __builtin_amdgcn_exp2f(x);
#else
  float r; asm("v_exp_f32 %0, %1" : "=v"(r) : "v"(x)); return r;
#endif
}
__device__ __forceinline__ float flog2(float x) {
#if __has_builtin(__builtin_amdgcn_logf)
  return __builtin_amdgcn_logf(x);
#else
  float r; asm("v_log_f32 %0, %1" : "=v"(r) : "v"(x)); return r;
#endif
}
__device__ __forceinline__ float frcp(float x) {
#if __has_builtin(__builtin_amdgcn_rcpf)
  return __builtin_amdgcn_rcpf(x);
#else
  float r; asm("v_rcp_f32 %0, %1" : "=v"(r) : "v"(x)); return r;
#endif
}

__device__ __forceinline__ f2 unpk(unsigned v) {
  f2 r;
  r.x = __uint_as_float(v << 16);
  r.y = __uint_as_float(v & 0xffff0000u);
  return r;
}

// ---------------- Wcat^T (bf16) prep, column-permuted layout ----------------
// oc<128: i-f (Wf rows 0..127); 128<=oc<256: i-s (Ws rows 0..127);
// oc>=256: j-interleaved t=oc-256, p=t>>2, r=t&3, c=2p+(r&1), r<2->Wf else Ws, rows 128..255
__global__ void prep_w(const float* __restrict__ Wf, const float* __restrict__ Ws,
                       unsigned short* __restrict__ whT) {
  int idx = blockIdx.x * 256 + threadIdx.x;   // 4*512*128 = 262144
  int k = idx & 127;
  int oc = (idx >> 7) & 511;
  int l = idx >> 16;
  const float* W;
  int row, c;
  if (oc < 128) { W = Wf; row = k; c = oc; }
  else if (oc < 256) { W = Ws; row = k; c = oc - 128; }
  else {
    int t = oc - 256;
    int p = t >> 2, r = t & 3;
    c = 2 * p + (r & 1);
    W = (r < 2) ? Wf : Ws;
    row = 128 + k;
  }
  whT[idx] = f2bf(W[(size_t)l * 32896 + (size_t)row * 128 + c]);
}

// ---------------- xh0 = bf16(emb[z]) + x-stats ----------------
__global__ __launch_bounds__(256) void gather_x(const float* __restrict__ emb,
                                                const int* __restrict__ z,
                                                unsigned short* __restrict__ xh,
                                                float* __restrict__ partial_x) {
  const int b = blockIdx.x, tid = threadIdx.x;   // 1000 blocks x 50 rows
  const int c4 = tid & 31, h = tid >> 5;
  const int r0 = b * FB_ROWS;
  float4 sx = {0, 0, 0, 0}, sx2 = {0, 0, 0, 0};
  for (int rr = h; rr < FB_ROWS; rr += 8) {
    int n = r0 + rr;
    float4 v = *(const float4*)(emb + (size_t)z[n] * EMBD + c4 * 4);
    ushort4 hh;
    hh.x = f2bf(v.x); hh.y = f2bf(v.y); hh.z = f2bf(v.z); hh.w = f2bf(v.w);
    *(ushort4*)(xh + (size_t)n * EMBD + c4 * 4) = hh;
    float o0 = bf2f(hh.x), o1 = bf2f(hh.y), o2 = bf2f(hh.z), o3 = bf2f(hh.w);
    sx.x += o0; sx.y += o1; sx.z += o2; sx.w += o3;
    sx2.x += o0 * o0; sx2.y += o1 * o1; sx2.z += o2 * o2; sx2.w += o3 * o3;
  }
  __shared__ float4 sm[256];
  float* p = partial_x + (size_t)b * 256;
#define REDUCE_STAT(V, OUTOFF)                                              \
  sm[tid] = V;                                                              \
  __syncthreads();                                                          \
  if (h == 0) {                                                             \
    float4 s = sm[tid];                                                     \
    for (int g = 1; g < 8; g++) {                                           \
      float4 o = sm[g * 32 + tid];                                          \
      s.x += o.x; s.y += o.y; s.z += o.z; s.w += o.w;                       \
    }                                                                       \
    *(float4*)(p + (OUTOFF) + c4 * 4) = s;                                  \
  }                                                                         \
  __syncthreads();
  REDUCE_STAT(sx, 0)
  REDUCE_STAT(sx2, 128)
#undef REDUCE_STAT
}

// ---------------- CSR build: one block per graph, all in LDS ----------------
__global__ __launch_bounds__(512) void csr_build(const int* __restrict__ ei,
                                                 const float* __restrict__ pos,
                                                 int* __restrict__ offs, int* __restrict__ deg,
                                                 uint2* __restrict__ csr) {
  __shared__ int hist[NPG];
  __shared__ int scan[512];
  const int g = blockIdx.x, t = threadIdx.x;
  const int nbase = g * NPG;
  const int e0 = g * EPG;
  for (int n = t; n < NPG; n += 512) hist[n] = 0;
  __syncthreads();
  for (int e = t; e < EPG; e += 512) atomicAdd(&hist[ei[NE + e0 + e] - nbase], 1);
  __syncthreads();
  int v = (t < NPG) ? hist[t] : 0;
  scan[t] = v;
  __syncthreads();
  for (int d = 1; d < 512; d <<= 1) {
    int a = (t >= d) ? scan[t - d] : 0;
    __syncthreads();
    scan[t] += a;
    __syncthreads();
  }
  if (t < NPG) {
    int off = scan[t] - v;
    offs[nbase + t] = e0 + off;
    deg[nbase + t] = v;
    hist[t] = off;
  }
  __syncthreads();
  for (int e = t; e < EPG; e += 512) {
    int j = ei[e0 + e];
    int i = ei[NE + e0 + e];
    float dx = pos[i * 3 + 0] - pos[j * 3 + 0];
    float dy = pos[i * 3 + 1] - pos[j * 3 + 1];
    float dz = pos[i * 3 + 2] - pos[j * 3 + 2];
    float dist = sqrtf(dx * dx + dy * dy + dz * dz);
    int p = atomicAdd(&hist[i - nbase], 1);
    csr[e0 + p] = make_uint2((unsigned)j, __float_as_uint(dist));
  }
}

// ---------------- P[n][512] = x(bf16) @ Wcat (MFMA 16x16x32 bf16) ----------------
// grid = dim3(4, 391): col-block fastest so 4 consecutive blocks share the A-tile
#define BM 128
#define BN 128
__global__ __launch_bounds__(256, 2) void gemm_proj(const unsigned short* __restrict__ xh,
                                                    const unsigned short* __restrict__ whT,
                                                    unsigned short* __restrict__ P, int l) {
  __shared__ __align__(16) unsigned short smem[32768];  // 64 KB: sA | sB, then sC view
  unsigned short* sA = smem;
  unsigned short* sB = smem + 16384;
  const int tid = threadIdx.x;
  const int R0 = blockIdx.y * BM;
  const int C0 = blockIdx.x * BN;
  for (int gid = tid; gid < BM * 16; gid += 256) {
    int row = gid >> 4, gc = gid & 15;
    int grow = R0 + row;
    uint4 v = make_uint4(0u, 0u, 0u, 0u);
    if (grow < NN) v = *(const uint4*)(xh + (size_t)grow * 128 + gc * 8);
    int gs = (gc & 8) | ((gc ^ row) & 7);
    *(uint4*)((char*)sA + row * 256 + gs * 16) = v;
  }
  for (int gid = tid; gid < BN * 16; gid += 256) {
    int c = gid >> 4, gc = gid & 15;
    uint4 v = *(const uint4*)(whT + ((size_t)l * 512 + C0 + c) * 128 + gc * 8);
    int gs = (gc & 8) | ((gc ^ c) & 7);
    *(uint4*)((char*)sB + c * 256 + gs * 16) = v;
  }
  __syncthreads();
  const int w = tid >> 6, lane = tid & 63;
  const int lr = lane & 15, lk = lane >> 4;
  float4v acc[2][8];
#pragma unroll
  for (int i = 0; i < 2; i++)
#pragma unroll
    for (int j = 0; j < 8; j++) acc[i][j] = (float4v){0.f, 0.f, 0.f, 0.f};
#pragma unroll
  for (int kb = 0; kb < 4; kb++) {
    int g = kb * 4 + lk;
    short8v a[2], b[8];
#pragma unroll
    for (int rf = 0; rf < 2; rf++) {
      int row = w * 32 + rf * 16 + lr;
      int gs = (g & 8) | ((g ^ row) & 7);
      a[rf] = *(const short8v*)((const char*)sA + row * 256 + gs * 16);
    }
#pragma unroll
    for (int cf = 0; cf < 8; cf++) {
      int c = cf * 16 + lr;
      int gs = (g & 8) | ((g ^ c) & 7);
      b[cf] = *(const short8v*)((const char*)sB + c * 256 + gs * 16);
    }
#pragma unroll
    for (int rf = 0; rf < 2; rf++)
#pragma unroll
      for (int cf = 0; cf < 8; cf++)
        acc[rf][cf] = __builtin_amdgcn_mfma_f32_16x16x32_bf16(a[rf], b[cf], acc[rf][cf], 0, 0, 0);
  }
  __syncthreads();
  unsigned short* sC = smem;  // 128*136 shorts
#pragma unroll
  for (int rf = 0; rf < 2; rf++) {
#pragma unroll
    for (int cf = 0; cf < 8; cf++) {
      int col = cf * 16 + lr;
#pragma unroll
      for (int j = 0; j < 4; j++) {
        int row = w * 32 + rf * 16 + lk * 4 + j;
        sC[row * 136 + col] = f2bf(acc[rf][cf][j]);
      }
    }
  }
  __syncthreads();
  for (int it = tid; it < BM * 16; it += 256) {
    int row = it >> 4, gc = it & 15;
    int grow = R0 + row;
    if (grow < NN) {
      uint4 v = *(const uint4*)(sC + row * 136 + gc * 8);
      *(uint4*)(P + (size_t)grow * 512 + C0 + gc * 8) = v;
    }
  }
}

// ---------------- edge gather: 16 nodes/block (4/wave), fused agg-stats ----------------
__global__ __launch_bounds__(256) void edge_gather(const unsigned short* __restrict__ P,
                                                   const uint2* __restrict__ csr,
                                                   const int* __restrict__ offs,
                                                   const int* __restrict__ deg,
                                                   const float* __restrict__ Wf,
                                                   const float* __restrict__ bf,
                                                   const float* __restrict__ Ws,
                                                   const float* __restrict__ bs,
                                                   const unsigned short* __restrict__ xh,
                                                   unsigned short* __restrict__ aggh,
                                                   float* __restrict__ partial_a, int l) {
  const float L = 1.4426950408889634f;   // log2(e)
  const float LN2 = 0.6931471805599453f;
  const int lane = threadIdx.x & 63;
  const int wid = __builtin_amdgcn_readfirstlane(threadIdx.x >> 6);
  // bijective XCD-chunked swizzle: nwg = 3125 = 8*390+5 -> q=390, r=5
  const int bid = blockIdx.x;
  const int xcd = bid & 7, bidx = bid >> 3;
  const int wg = (xcd < 5) ? xcd * 391 + bidx : 5 * 391 + (xcd - 5) * 390 + bidx;
  const int f0 = lane * 2;

  float2 wfd = *(const float2*)(Wf + (size_t)l * 32896 + 256 * 128 + f0);
  float2 wsd = *(const float2*)(Ws + (size_t)l * 32896 + 256 * 128 + f0);
  float2 bfv = *(const float2*)(bf + l * 128 + f0);
  float2 bsv = *(const float2*)(bs + l * 128 + f0);
  f2 wflv, wslv;
  wflv.x = wfd.x * L; wflv.y = wfd.y * L;
  wslv.x = wsd.x * L; wslv.y = wsd.y * L;

  f2 sa = (f2){0.f, 0.f}, sa2 = (f2){0.f, 0.f}, sax = (f2){0.f, 0.f};

#define EDGE_BODY(DVU, V)                                          \
  {                                                                \
    float dv = __uint_as_float(DVU);                               \
    f2 pf = unpk((V).x) * L + (bflv + dv * wflv);                  \
    f2 ps = unpk((V).y) * L + (bslv + dv * wslv);                  \
    f2 a, b, r, lg;                                                \
    a.x = fexp2(-pf.x); a.y = fexp2(-pf.y);                        \
    b.x = fexp2(ps.x);  b.y = fexp2(ps.y);                         \
    r.x = frcp(a.x + 1.f); r.y = frcp(a.y + 1.f);                  \
    lg.x = flog2(b.x + 1.f); lg.y = flog2(b.y + 1.f);              \
    acc += r * lg;                                                 \
  }

  for (int n = 0; n < 4; n++) {
    const int i = wg * 16 + wid * 4 + n;
    const unsigned* Piu = (const unsigned*)(P + (size_t)i * 512);
    unsigned pif = Piu[lane];       // i-f (cols 0..127)
    unsigned pis = Piu[64 + lane];  // i-s (cols 128..255)
    f2 bflv, bslv;
    {
      f2 pi_f = unpk(pif), pi_s = unpk(pis);
      bflv.x = (pi_f.x + bfv.x) * L; bflv.y = (pi_f.y + bfv.y) * L;
      bslv.x = (pi_s.x + bsv.x) * L; bslv.y = (pi_s.y + bsv.y) * L;
    }
    const int off = __builtin_amdgcn_readfirstlane(offs[i]);
    const int nd = __builtin_amdgcn_readfirstlane(deg[i]);
    const uint2* ep = csr + off;
    f2 acc = (f2){0.f, 0.f};
    int k = 0;
    for (; k + 3 < nd; k += 4) {
      uint2 e0 = ep[k], e1 = ep[k + 1], e2 = ep[k + 2], e3 = ep[k + 3];
      unsigned j0 = __builtin_amdgcn_readfirstlane(e0.x);
      unsigned j1 = __builtin_amdgcn_readfirstlane(e1.x);
      unsigned j2 = __builtin_amdgcn_readfirstlane(e2.x);
      unsigned j3 = __builtin_amdgcn_readfirstlane(e3.x);
      unsigned d0 = __builtin_amdgcn_readfirstlane(e0.y);
      unsigned d1 = __builtin_amdgcn_readfirstlane(e1.y);
      unsigned d2 = __builtin_amdgcn_readfirstlane(e2.y);
      unsigned d3 = __builtin_amdgcn_readfirstlane(e3.y);
      uint2 v0 = ((const uint2*)(P + (size_t)j0 * 512))[64 + lane];
      uint2 v1 = ((const uint2*)(P + (size_t)j1 * 512))[64 + lane];
      uint2 v2 = ((const uint2*)(P + (size_t)j2 * 512))[64 + lane];
      uint2 v3 = ((const uint2*)(P + (size_t)j3 * 512))[64 + lane];
      EDGE_BODY(d0, v0)
      EDGE_BODY(d1, v1)
      EDGE_BODY(d2, v2)
      EDGE_BODY(d3, v3)
    }
    for (; k < nd; k++) {
      uint2 e0 = ep[k];
      unsigned j0 = __builtin_amdgcn_readfirstlane(e0.x);
      unsigned d0 = __builtin_amdgcn_readfirstlane(e0.y);
      uint2 v0 = ((const uint2*)(P + (size_t)j0 * 512))[64 + lane];
      EDGE_BODY(d0, v0)
    }
    acc.x *= LN2; acc.y *= LN2;
    unsigned packed = ((unsigned)f2bf(acc.y) << 16) | (unsigned)f2bf(acc.x);
    ((unsigned*)(aggh + (size_t)i * EMBD))[lane] = packed;
    // stats on the rounded (stored) values, matching previous col_stats semantics
    f2 aggr = unpk(packed);
    f2 xv = unpk(((const unsigned*)(xh + (size_t)i * EMBD))[lane]);
    sa += aggr;
    sa2 += aggr * aggr;
    sax += aggr * xv;
  }
#undef EDGE_BODY

  // cross-wave LDS reduce: 4 waves x 64 lanes x 6 floats
  __shared__ float sm[4 * 64 * 6];
  int base = (wid * 64 + lane) * 6;
  sm[base + 0] = sa.x; sm[base + 1] = sa.y;
  sm[base + 2] = sa2.x; sm[base + 3] = sa2.y;
  sm[base + 4] = sax.x; sm[base + 5] = sax.y;
  __syncthreads();
  if (wid == 0) {
    f2 ta = sa, ta2 = sa2, tax = sax;
    for (int w2 = 1; w2 < 4; w2++) {
      int b2 = (w2 * 64 + lane) * 6;
      ta.x += sm[b2 + 0]; ta.y += sm[b2 + 1];
      ta2.x += sm[b2 + 2]; ta2.y += sm[b2 + 3];
      tax.x += sm[b2 + 4]; tax.y += sm[b2 + 5];
    }
    float* p = partial_a + (size_t)bid * 384;
    *(float2*)(p + f0) = make_float2(ta.x, ta.y);
    *(float2*)(p + 128 + f0) = make_float2(ta2.x, ta2.y);
    *(float2*)(p + 256 + f0) = make_float2(tax.x, tax.y);
  }
}

// ---------------- fold: partial_a[3125][384] + partial_x[1000][256] -> abc ----------------
__global__ __launch_bounds__(256) void bn_fold(const float* __restrict__ partial_a,
                                               const float* __restrict__ partial_x,
                                               const float* __restrict__ bn1g,
                                               const float* __restrict__ bn1b,
                                               const float* __restrict__ bn2g,
                                               const float* __restrict__ bn2b,
                                               float* __restrict__ abc, int l) {
  __shared__ float sm[5 * 256];
  const int t = threadIdx.x;
  const int ci = t & 7;                    // 16 blocks x 8 cols
  const int col = blockIdx.x * 8 + ci;
  const int chunk = t >> 3;                // 32 chunks
  float s0 = 0, s1 = 0, s2 = 0, s3 = 0, s4 = 0;
  for (int b = chunk; b < EB_BLOCKS; b += 32) {
    const float* p = partial_a + (size_t)b * 384 + col;
    s0 += p[0]; s1 += p[128]; s2 += p[256];     // sa, sa2, sax
  }
  for (int b = chunk; b < FB_BLOCKS; b += 32) {
    const float* p = partial_x + (size_t)b * 256 + col;
    s3 += p[0]; s4 += p[128];                   // sx, sx2
  }
  sm[t] = s0; sm[256 + t] = s1; sm[512 + t] = s2; sm[768 + t] = s3; sm[1024 + t] = s4;
  __syncthreads();
  if (t < 8) {
    int c = blockIdx.x * 8 + t;
    float a0 = 0, a1 = 0, a2 = 0, a3 = 0, a4 = 0;
    for (int ch = 0; ch < 32; ch++) {
      int u = ch * 8 + t;
      a0 += sm[u]; a1 += sm[256 + u]; a2 += sm[512 + u]; a3 += sm[768 + u]; a4 += sm[1024 + u];
    }
    const double Ninv = 1.0 / (double)NN;
    double Ea = a0 * Ninv, Ea2 = a1 * Ninv, Eax = a2 * Ninv, Ex = a3 * Ninv, Ex2 = a4 * Ninv;
    double var1 = Ea2 - Ea * Ea;
    double g1 = bn1g[l * 128 + c], b1 = bn1b[l * 128 + c];
    double g2 = bn2g[l * 128 + c], b2v = bn2b[l * 128 + c];
    double s1d = g1 / sqrt(var1 + 1e-5);
    double t1 = b1 - Ea * s1d;
    double mu_o = s1d * Ea + t1 + Ex;
    double Eo2 = s1d * s1d * Ea2 + 2.0 * s1d * t1 * Ea + t1 * t1 + 2.0 * (s1d * Eax + t1 * Ex) + Ex2;
    double var_o = Eo2 - mu_o * mu_o;
    double s2d = g2 / sqrt(var_o + 1e-5);
    double t2 = b2v - mu_o * s2d;
    abc[c] = (float)(s1d * s2d);
    abc[128 + c] = (float)s2d;
    abc[256 + c] = (float)(t1 * s2d + t2);
  }
}

// ---------------- xh = bf16(relu(A*agg + B*x + C)) + next-layer x-stats ----------------
__global__ __launch_bounds__(256) void fuse_bn(const unsigned short* __restrict__ aggh,
                                               unsigned short* __restrict__ xh,
                                               const float* __restrict__ abc,
                                               float* __restrict__ partial_x) {
  const int b = blockIdx.x, tid = threadIdx.x;   // 1000 blocks x 50 rows
  const int c4 = tid & 31, h = tid >> 5;
  const int r0 = b * FB_ROWS;
  float4 A = *(const float4*)(abc + c4 * 4);
  float4 B = *(const float4*)(abc + 128 + c4 * 4);
  float4 C = *(const float4*)(abc + 256 + c4 * 4);
  float4 sx = {0, 0, 0, 0}, sx2 = {0, 0, 0, 0};
  for (int rr = h; rr < FB_ROWS; rr += 8) {
    size_t base = (size_t)(r0 + rr) * EMBD + c4 * 4;
    ushort4 ha = *(const ushort4*)(aggh + base);
    ushort4 hx = *(const ushort4*)(xh + base);
    float4 o;
    o.x = fmaxf(fmaf(A.x, bf2f(ha.x), fmaf(B.x, bf2f(hx.x), C.x)), 0.f);
    o.y = fmaxf(fmaf(A.y, bf2f(ha.y), fmaf(B.y, bf2f(hx.y), C.y)), 0.f);
    o.z = fmaxf(fmaf(A.z, bf2f(ha.z), fmaf(B.z, bf2f(hx.z), C.z)), 0.f);
    o.w = fmaxf(fmaf(A.w, bf2f(ha.w), fmaf(B.w, bf2f(hx.w), C.w)), 0.f);
    ushort4 hh;
    hh.x = f2bf(o.x); hh.y = f2bf(o.y); hh.z = f2bf(o.z); hh.w = f2bf(o.w);
    *(ushort4*)(xh + base) = hh;
    float o0 = bf2f(hh.x), o1 = bf2f(hh.y), o2 = bf2f(hh.z), o3 = bf2f(hh.w);
    sx.x += o0; sx.y += o1; sx.z += o2; sx.w += o3;
    sx2.x += o0 * o0; sx2.y += o1 * o1; sx2.z += o2 * o2; sx2.w += o3 * o3;
  }
  __shared__ float4 sm[256];
  float* p = partial_x + (size_t)b * 256;
#define REDUCE_STAT(V, OUTOFF)                                              \
  sm[tid] = V;                                                              \
  __syncthreads();                                                          \
  if (h == 0) {                                                             \
    float4 s = sm[tid];                                                     \
    for (int g = 1; g < 8; g++) {                                           \
      float4 o = sm[g * 32 + tid];                                          \
      s.x += o.x; s.y += o.y; s.z += o.z; s.w += o.w;                       \
    }                                                                       \
    *(float4*)(p + (OUTOFF) + c4 * 4) = s;                                  \
  }                                                                         \
  __syncthreads();
  REDUCE_STAT(sx, 0)
  REDUCE_STAT(sx2, 128)
#undef REDUCE_STAT
}

// ---------------- global mean pool + final MLP (merged) ----------------
__global__ __launch_bounds__(512) void pool_mlp(const unsigned short* __restrict__ xh,
                                                const float* __restrict__ W1,
                                                const float* __restrict__ b1,
                                                const float* __restrict__ W2,
                                                const float* __restrict__ b2,
                                                float* __restrict__ out) {
  __shared__ float red[512];
  __shared__ float gl[128];
  const int g = blockIdx.x, t = threadIdx.x;
  const int c = t & 127, q = t >> 7;
  const unsigned short* bx = xh + (size_t)g * NPG * EMBD;
  float s = 0.f;
  for (int r = q; r < NPG; r += 4) s += bf2f(bx[(size_t)r * EMBD + c]);
  red[t] = s;
  __syncthreads();
  if (q == 0) gl[c] = (red[c] + red[128 + c] + red[256 + c] + red[384 + c]) * (1.f / NPG);
  __syncthreads();
  float acc = 0.f;
  for (int k = q * 32; k < q * 32 + 32; k++) acc = fmaf(gl[k], W1[k * EMBD + c], acc);
  red[t] = acc;
  __syncthreads();
  if (q == 0) {
    float h = fmaxf(red[c] + red[128 + c] + red[256 + c] + red[384 + c] + b1[c], 0.f);
    red[c] = h * W2[c];
  }
  __syncthreads();
  for (int sft = 64; sft > 0; sft >>= 1) {
    if (t < sft) red[t] += red[t + sft];
    __syncthreads();
  }
  if (t == 0) out[g] = red[0] + b2[0];
}

extern "C" void kernel_launch(void* const* d_in, const int* in_sizes, int n_in,
                              void* d_out, int out_size, void* d_ws, size_t ws_size,
                              hipStream_t stream) {
  const float* pos = (const float*)d_in[0];
  const float* emb = (const float*)d_in[1];
  const float* Wf = (const float*)d_in[2];
  const float* bf = (const float*)d_in[3];
  const float* Ws = (const float*)d_in[4];
  const float* bs = (const float*)d_in[5];
  const float* bn1g = (const float*)d_in[6];
  const float* bn1b = (const float*)d_in[7];
  const float* bn2g = (const float*)d_in[8];
  const float* bn2b = (const float*)d_in[9];
  const float* W1 = (const float*)d_in[10];
  const float* b1 = (const float*)d_in[11];
  const float* W2 = (const float*)d_in[12];
  const float* b2 = (const float*)d_in[13];
  const int* z = (const int*)d_in[14];
  const int* ei = (const int*)d_in[16];
  float* out = (float*)d_out;

  char* ws = (char*)d_ws;
  unsigned short* xh = (unsigned short*)(ws + 0);            // 12,800,000
  unsigned short* P = (unsigned short*)(ws + 12800000);      // 51,200,000
  unsigned short* aggh = (unsigned short*)(ws + 64000000);   // 12,800,000
  uint2* csr = (uint2*)(ws + 76800000);                      //  6,400,000
  int* deg = (int*)(ws + 83200000);                          //    200,000
  int* offs = (int*)(ws + 83400000);                         //    200,000
  unsigned short* whT = (unsigned short*)(ws + 83600000);    //    524,288
  float* partial_a = (float*)(ws + 84124288);                //  4,800,000
  float* partial_x = (float*)(ws + 88924288);                //  1,024,000
  float* abc = (float*)(ws + 89948288);                      //      1,536

  prep_w<<<1024, 256, 0, stream>>>(Wf, Ws, whT);
  gather_x<<<FB_BLOCKS, 256, 0, stream>>>(emb, z, xh, partial_x);
  csr_build<<<NG, 512, 0, stream>>>(ei, pos, offs, deg, csr);
  for (int l = 0; l < NL; l++) {
    gemm_proj<<<dim3(4, 391), 256, 0, stream>>>(xh, whT, P, l);
    edge_gather<<<EB_BLOCKS, 256, 0, stream>>>(P, csr, offs, deg, Wf, bf, Ws, bs, xh, aggh,
                                               partial_a, l);
    bn_fold<<<16, 256, 0, stream>>>(partial_a, partial_x, bn1g, bn1b, bn2g, bn2b, abc, l);
    fuse_bn<<<FB_BLOCKS, 256, 0, stream>>>(aggh, xh, abc, partial_x);
  }
  pool_mlp<<<NG, 512, 0, stream>>>(xh, W1, b1, W2, b2, out);
}

// Round 11
// 551.856 us; speedup vs baseline: 1.1212x; 1.1212x over previous
//
#include <hip/hip_runtime.h>

#define NN 50000
#define NG 100
#define NPG 500
#define NE 800000
#define EPG 8000
#define EMBD 128
#define NL 4
#define CS_BLOCKS 1000
#define CS_ROWS 50

typedef __attribute__((ext_vector_type(8))) short short8v;
typedef __attribute__((ext_vector_type(4))) float float4v;
typedef __attribute__((ext_vector_type(2))) float f2;

__device__ __forceinline__ unsigned short f2bf(float v) {
  unsigned u = __float_as_uint(v);
  u += 0x7FFFu + ((u >> 16) & 1u);
  return (unsigned short)(u >> 16);
}
__device__ __forceinline__ float bf2f(unsigned short h) {
  return __uint_as_float(((unsigned)h) << 16);
}

__device__ __forceinline__ float fexp2(float x) {
#if __has_builtin(__builtin_amdgcn_exp2f)
  return __builtin_amdgcn_exp2f(x);
#else
  float r; asm("v_exp_f32 %0, %1" : "=v"(r) : "v"(x)); return r;
#endif
}
__device__ __forceinline__ float flog2(float x) {
#if __has_builtin(__builtin_amdgcn_logf)
  return __builtin_amdgcn_logf(x);
#else
  float r; asm("v_log_f32 %0, %1" : "=v"(r) : "v"(x)); return r;
#endif
}
__device__ __forceinline__ float frcp(float x) {
#if __has_builtin(__builtin_amdgcn_rcpf)
  return __builtin_amdgcn_rcpf(x);
#else
  float r; asm("v_rcp_f32 %0, %1" : "=v"(r) : "v"(x)); return r;
#endif
}

__device__ __forceinline__ f2 unpk(unsigned v) {
  f2 r;
  r.x = __uint_as_float(v << 16);
  r.y = __uint_as_float(v & 0xffff0000u);
  return r;
}

// ---------------- Wcat^T (bf16) prep, column-permuted layout ----------------
// oc<128: i-f (Wf rows 0..127); 128<=oc<256: i-s (Ws rows 0..127);
// oc>=256: j-interleaved t=oc-256, p=t>>2, r=t&3, c=2p+(r&1), r<2->Wf else Ws, rows 128..255
__global__ void prep_w(const float* __restrict__ Wf, const float* __restrict__ Ws,
                       unsigned short* __restrict__ whT) {
  int idx = blockIdx.x * 256 + threadIdx.x;   // 4*512*128 = 262144
  int k = idx & 127;
  int oc = (idx >> 7) & 511;
  int l = idx >> 16;
  const float* W;
  int row, c;
  if (oc < 128) { W = Wf; row = k; c = oc; }
  else if (oc < 256) { W = Ws; row = k; c = oc - 128; }
  else {
    int t = oc - 256;
    int p = t >> 2, r = t & 3;
    c = 2 * p + (r & 1);
    W = (r < 2) ? Wf : Ws;
    row = 128 + k;
  }
  whT[idx] = f2bf(W[(size_t)l * 32896 + (size_t)row * 128 + c]);
}

// ---------------- xh0 = bf16(emb[z]) ----------------
__global__ void gather_x(const float* __restrict__ emb, const int* __restrict__ z,
                         unsigned short* __restrict__ xh) {
  const int total = NN * 32;
  for (int idx = blockIdx.x * 256 + threadIdx.x; idx < total; idx += gridDim.x * 256) {
    int n = idx >> 5, c4 = (idx & 31) * 4;
    float4 v = *(const float4*)(emb + (size_t)z[n] * EMBD + c4);
    ushort4 h;
    h.x = f2bf(v.x); h.y = f2bf(v.y); h.z = f2bf(v.z); h.w = f2bf(v.w);
    *(ushort4*)(xh + (size_t)idx * 4) = h;
  }
}

// ---------------- CSR build: one block per graph, all in LDS ----------------
__global__ __launch_bounds__(512) void csr_build(const int* __restrict__ ei,
                                                 const float* __restrict__ pos,
                                                 int* __restrict__ offs, int* __restrict__ deg,
                                                 uint2* __restrict__ csr) {
  __shared__ int hist[NPG];
  __shared__ int scan[512];
  const int g = blockIdx.x, t = threadIdx.x;
  const int nbase = g * NPG;
  const int e0 = g * EPG;
  for (int n = t; n < NPG; n += 512) hist[n] = 0;
  __syncthreads();
  for (int e = t; e < EPG; e += 512) atomicAdd(&hist[ei[NE + e0 + e] - nbase], 1);
  __syncthreads();
  int v = (t < NPG) ? hist[t] : 0;
  scan[t] = v;
  __syncthreads();
  for (int d = 1; d < 512; d <<= 1) {
    int a = (t >= d) ? scan[t - d] : 0;
    __syncthreads();
    scan[t] += a;
    __syncthreads();
  }
  if (t < NPG) {
    int off = scan[t] - v;
    offs[nbase + t] = e0 + off;
    deg[nbase + t] = v;
    hist[t] = off;
  }
  __syncthreads();
  for (int e = t; e < EPG; e += 512) {
    int j = ei[e0 + e];
    int i = ei[NE + e0 + e];
    float dx = pos[i * 3 + 0] - pos[j * 3 + 0];
    float dy = pos[i * 3 + 1] - pos[j * 3 + 1];
    float dz = pos[i * 3 + 2] - pos[j * 3 + 2];
    float dist = sqrtf(dx * dx + dy * dy + dz * dz);
    int p = atomicAdd(&hist[i - nbase], 1);
    csr[e0 + p] = make_uint2((unsigned)j, __float_as_uint(dist));
  }
}

// ---------------- P = x(bf16) @ Wcat, with fused BN on A-stage (l>0) ----------------
// grid = dim3(4, 391): col-block fastest so 4 consecutive blocks share the A-tile.
// For l>0: A-input x_in(l) = relu(A*agg + B*x_in(l-1) + C) computed on the fly;
// blockIdx.x==0 also materializes it to xh_new (consumed by col_stats / next layer).
#define BM 128
#define BN 128
__global__ __launch_bounds__(256, 2) void gemm_proj(const unsigned short* __restrict__ xh_old,
                                                    const unsigned short* __restrict__ aggh,
                                                    const float* __restrict__ abc,
                                                    const unsigned short* __restrict__ whT,
                                                    unsigned short* __restrict__ P,
                                                    unsigned short* __restrict__ xh_new, int l) {
  __shared__ __align__(16) unsigned short smem[32768];  // 64 KB: sA | sB, then sC view
  __shared__ float sABC[384];
  unsigned short* sA = smem;
  unsigned short* sB = smem + 16384;
  const int tid = threadIdx.x;
  const int R0 = blockIdx.y * BM;
  const int C0 = blockIdx.x * BN;
  if (l > 0) {
    for (int t = tid; t < 384; t += 256) sABC[t] = abc[t];
  }
  __syncthreads();
  for (int gid = tid; gid < BM * 16; gid += 256) {
    int row = gid >> 4, gc = gid & 15;
    int grow = R0 + row;
    uint4 v = make_uint4(0u, 0u, 0u, 0u);
    if (grow < NN) {
      if (l == 0) {
        v = *(const uint4*)(xh_old + (size_t)grow * 128 + gc * 8);
      } else {
        uint4 va = *(const uint4*)(aggh + (size_t)grow * 128 + gc * 8);
        uint4 vx = *(const uint4*)(xh_old + (size_t)grow * 128 + gc * 8);
        const unsigned* pa = (const unsigned*)&va;
        const unsigned* px = (const unsigned*)&vx;
        unsigned* pv = (unsigned*)&v;
#pragma unroll
        for (int q = 0; q < 4; q++) {
          f2 ag = unpk(pa[q]), xv = unpk(px[q]);
          int c0 = gc * 8 + q * 2;
          float o0 = fmaxf(fmaf(sABC[c0], ag.x, fmaf(sABC[128 + c0], xv.x, sABC[256 + c0])), 0.f);
          float o1 = fmaxf(fmaf(sABC[c0 + 1], ag.y, fmaf(sABC[129 + c0], xv.y, sABC[257 + c0])), 0.f);
          pv[q] = ((unsigned)f2bf(o1) << 16) | (unsigned)f2bf(o0);
        }
        if (C0 == 0) *(uint4*)(xh_new + (size_t)grow * 128 + gc * 8) = v;
      }
    }
    int gs = (gc & 8) | ((gc ^ row) & 7);
    *(uint4*)((char*)sA + row * 256 + gs * 16) = v;
  }
  for (int gid = tid; gid < BN * 16; gid += 256) {
    int c = gid >> 4, gc = gid & 15;
    uint4 v = *(const uint4*)(whT + ((size_t)l * 512 + C0 + c) * 128 + gc * 8);
    int gs = (gc & 8) | ((gc ^ c) & 7);
    *(uint4*)((char*)sB + c * 256 + gs * 16) = v;
  }
  __syncthreads();
  const int w = tid >> 6, lane = tid & 63;
  const int lr = lane & 15, lk = lane >> 4;
  float4v acc[2][8];
#pragma unroll
  for (int i = 0; i < 2; i++)
#pragma unroll
    for (int j = 0; j < 8; j++) acc[i][j] = (float4v){0.f, 0.f, 0.f, 0.f};
#pragma unroll
  for (int kb = 0; kb < 4; kb++) {
    int g = kb * 4 + lk;
    short8v a[2], b[8];
#pragma unroll
    for (int rf = 0; rf < 2; rf++) {
      int row = w * 32 + rf * 16 + lr;
      int gs = (g & 8) | ((g ^ row) & 7);
      a[rf] = *(const short8v*)((const char*)sA + row * 256 + gs * 16);
    }
#pragma unroll
    for (int cf = 0; cf < 8; cf++) {
      int c = cf * 16 + lr;
      int gs = (g & 8) | ((g ^ c) & 7);
      b[cf] = *(const short8v*)((const char*)sB + c * 256 + gs * 16);
    }
#pragma unroll
    for (int rf = 0; rf < 2; rf++)
#pragma unroll
      for (int cf = 0; cf < 8; cf++)
        acc[rf][cf] = __builtin_amdgcn_mfma_f32_16x16x32_bf16(a[rf], b[cf], acc[rf][cf], 0, 0, 0);
  }
  __syncthreads();
  unsigned short* sC = smem;  // 128*136 shorts
#pragma unroll
  for (int rf = 0; rf < 2; rf++) {
#pragma unroll
    for (int cf = 0; cf < 8; cf++) {
      int col = cf * 16 + lr;
#pragma unroll
      for (int j = 0; j < 4; j++) {
        int row = w * 32 + rf * 16 + lk * 4 + j;
        sC[row * 136 + col] = f2bf(acc[rf][cf][j]);
      }
    }
  }
  __syncthreads();
  for (int it = tid; it < BM * 16; it += 256) {
    int row = it >> 4, gc = it & 15;
    int grow = R0 + row;
    if (grow < NN) {
      uint4 v = *(const uint4*)(sC + row * 136 + gc * 8);
      *(uint4*)(P + (size_t)grow * 512 + C0 + gc * 8) = v;
    }
  }
}

// ---------------- edge gather: one wave per dst node, simple 4-unroll + XCD swizzle ----------------
__global__ __launch_bounds__(256) void edge_gather(const unsigned short* __restrict__ P,
                                                   const uint2* __restrict__ csr,
                                                   const int* __restrict__ offs,
                                                   const int* __restrict__ deg,
                                                   const float* __restrict__ Wf,
                                                   const float* __restrict__ bf,
                                                   const float* __restrict__ Ws,
                                                   const float* __restrict__ bs,
                                                   unsigned short* __restrict__ aggh, int l) {
  const float L = 1.4426950408889634f;   // log2(e)
  const float LN2 = 0.6931471805599453f;
  const int lane = threadIdx.x & 63;
  const int wid = __builtin_amdgcn_readfirstlane(threadIdx.x >> 6);
  // bijective XCD-chunked swizzle: nwg = 12500, q = 1562, r = 4
  const int bid = blockIdx.x;
  const int xcd = bid & 7, bidx = bid >> 3;
  const int wg = (xcd < 4) ? xcd * 1563 + bidx : 4 * 1563 + (xcd - 4) * 1562 + bidx;
  const int i = wg * 4 + wid;
  const int f0 = lane * 2;

  const unsigned* Piu = (const unsigned*)(P + (size_t)i * 512);
  unsigned pif = Piu[lane];       // i-f (cols 0..127)
  unsigned pis = Piu[64 + lane];  // i-s (cols 128..255)

  float2 wfd = *(const float2*)(Wf + (size_t)l * 32896 + 256 * 128 + f0);
  float2 wsd = *(const float2*)(Ws + (size_t)l * 32896 + 256 * 128 + f0);
  float2 bfv = *(const float2*)(bf + l * 128 + f0);
  float2 bsv = *(const float2*)(bs + l * 128 + f0);

  f2 bflv, bslv, wflv, wslv;
  {
    f2 pi_f = unpk(pif), pi_s = unpk(pis);
    bflv.x = (pi_f.x + bfv.x) * L; bflv.y = (pi_f.y + bfv.y) * L;
    bslv.x = (pi_s.x + bsv.x) * L; bslv.y = (pi_s.y + bsv.y) * L;
    wflv.x = wfd.x * L; wflv.y = wfd.y * L;
    wslv.x = wsd.x * L; wslv.y = wsd.y * L;
  }

  const int off = __builtin_amdgcn_readfirstlane(offs[i]);
  const int nd = __builtin_amdgcn_readfirstlane(deg[i]);
  const uint2* ep = csr + off;
  f2 acc = (f2){0.f, 0.f};

#define EDGE_BODY(DVU, V)                                          \
  {                                                                \
    float dv = __uint_as_float(DVU);                               \
    f2 pf = unpk((V).x) * L + (bflv + dv * wflv);                  \
    f2 ps = unpk((V).y) * L + (bslv + dv * wslv);                  \
    f2 a, b, r, lg;                                                \
    a.x = fexp2(-pf.x); a.y = fexp2(-pf.y);                        \
    b.x = fexp2(ps.x);  b.y = fexp2(ps.y);                         \
    r.x = frcp(a.x + 1.f); r.y = frcp(a.y + 1.f);                  \
    lg.x = flog2(b.x + 1.f); lg.y = flog2(b.y + 1.f);              \
    acc += r * lg;                                                 \
  }

  int k = 0;
  for (; k + 3 < nd; k += 4) {
    uint2 e0 = ep[k], e1 = ep[k + 1], e2 = ep[k + 2], e3 = ep[k + 3];
    unsigned j0 = __builtin_amdgcn_readfirstlane(e0.x);
    unsigned j1 = __builtin_amdgcn_readfirstlane(e1.x);
    unsigned j2 = __builtin_amdgcn_readfirstlane(e2.x);
    unsigned j3 = __builtin_amdgcn_readfirstlane(e3.x);
    unsigned d0 = __builtin_amdgcn_readfirstlane(e0.y);
    unsigned d1 = __builtin_amdgcn_readfirstlane(e1.y);
    unsigned d2 = __builtin_amdgcn_readfirstlane(e2.y);
    unsigned d3 = __builtin_amdgcn_readfirstlane(e3.y);
    uint2 v0 = ((const uint2*)(P + (size_t)j0 * 512))[64 + lane];
    uint2 v1 = ((const uint2*)(P + (size_t)j1 * 512))[64 + lane];
    uint2 v2 = ((const uint2*)(P + (size_t)j2 * 512))[64 + lane];
    uint2 v3 = ((const uint2*)(P + (size_t)j3 * 512))[64 + lane];
    EDGE_BODY(d0, v0)
    EDGE_BODY(d1, v1)
    EDGE_BODY(d2, v2)
    EDGE_BODY(d3, v3)
  }
  for (; k < nd; k++) {
    uint2 e0 = ep[k];
    unsigned j0 = __builtin_amdgcn_readfirstlane(e0.x);
    unsigned d0 = __builtin_amdgcn_readfirstlane(e0.y);
    uint2 v0 = ((const uint2*)(P + (size_t)j0 * 512))[64 + lane];
    EDGE_BODY(d0, v0)
  }
#undef EDGE_BODY

  acc.x *= LN2; acc.y *= LN2;
  unsigned packed = ((unsigned)f2bf(acc.y) << 16) | (unsigned)f2bf(acc.x);
  ((unsigned*)(aggh + (size_t)i * EMBD))[lane] = packed;
}

// ---------------- col stats: agg bf16 + x bf16 ----------------
__global__ __launch_bounds__(256) void col_stats(const unsigned short* __restrict__ aggh,
                                                 const unsigned short* __restrict__ xh,
                                                 float* __restrict__ partial) {
  const int b = blockIdx.x, tid = threadIdx.x;
  const int c4 = tid & 31;
  const int h = tid >> 5;
  const int r0 = b * CS_ROWS;
  float4 sa = {0, 0, 0, 0}, sa2 = {0, 0, 0, 0}, sx = {0, 0, 0, 0}, sx2 = {0, 0, 0, 0},
         sax = {0, 0, 0, 0};
  for (int rr = h; rr < CS_ROWS; rr += 8) {
    size_t idx = (size_t)(r0 + rr) * EMBD + c4 * 4;
    ushort4 ha = *(const ushort4*)(aggh + idx);
    ushort4 hx = *(const ushort4*)(xh + idx);
    float a0 = bf2f(ha.x), a1 = bf2f(ha.y), a2 = bf2f(ha.z), a3 = bf2f(ha.w);
    float x0 = bf2f(hx.x), x1 = bf2f(hx.y), x2 = bf2f(hx.z), x3 = bf2f(hx.w);
    sa.x += a0; sa.y += a1; sa.z += a2; sa.w += a3;
    sa2.x += a0 * a0; sa2.y += a1 * a1; sa2.z += a2 * a2; sa2.w += a3 * a3;
    sx.x += x0; sx.y += x1; sx.z += x2; sx.w += x3;
    sx2.x += x0 * x0; sx2.y += x1 * x1; sx2.z += x2 * x2; sx2.w += x3 * x3;
    sax.x += a0 * x0; sax.y += a1 * x1; sax.z += a2 * x2; sax.w += a3 * x3;
  }
  __shared__ float4 sm[256];
  float* p = partial + (size_t)b * 640;
#define REDUCE_STAT(V, OUTOFF)                                              \
  sm[tid] = V;                                                              \
  __syncthreads();                                                          \
  if (h == 0) {                                                             \
    float4 s = sm[tid];                                                     \
    for (int g = 1; g < 8; g++) {                                           \
      float4 o = sm[g * 32 + tid];                                          \
      s.x += o.x; s.y += o.y; s.z += o.z; s.w += o.w;                       \
    }                                                                       \
    *(float4*)(p + (OUTOFF) + c4 * 4) = s;                                  \
  }                                                                         \
  __syncthreads();
  REDUCE_STAT(sa, 0)
  REDUCE_STAT(sa2, 128)
  REDUCE_STAT(sx, 256)
  REDUCE_STAT(sx2, 384)
  REDUCE_STAT(sax, 512)
#undef REDUCE_STAT
}

// ---------------- fold: partial[1000][640] -> BN coeffs, 8 blocks x 16 cols ----------------
__global__ __launch_bounds__(256) void bn_fold(const float* __restrict__ partial,
                                               const float* __restrict__ bn1g,
                                               const float* __restrict__ bn1b,
                                               const float* __restrict__ bn2g,
                                               const float* __restrict__ bn2b,
                                               float* __restrict__ abc, int l) {
  __shared__ float sm[5 * 256];
  const int t = threadIdx.x;
  const int ci = t & 15;
  const int col = blockIdx.x * 16 + ci;
  const int chunk = t >> 4;
  float s0 = 0, s1 = 0, s2 = 0, s3 = 0, s4 = 0;
  for (int b = chunk; b < CS_BLOCKS; b += 16) {
    const float* p = partial + (size_t)b * 640 + col;
    s0 += p[0]; s1 += p[128]; s2 += p[256]; s3 += p[384]; s4 += p[512];
  }
  sm[t] = s0; sm[256 + t] = s1; sm[512 + t] = s2; sm[768 + t] = s3; sm[1024 + t] = s4;
  __syncthreads();
  if (t < 16) {
    int c = blockIdx.x * 16 + t;
    float a0 = 0, a1 = 0, a2 = 0, a3 = 0, a4 = 0;
    for (int ch = 0; ch < 16; ch++) {
      int u = ch * 16 + t;
      a0 += sm[u]; a1 += sm[256 + u]; a2 += sm[512 + u]; a3 += sm[768 + u]; a4 += sm[1024 + u];
    }
    const double Ninv = 1.0 / (double)NN;
    double Ea = a0 * Ninv, Ea2 = a1 * Ninv, Ex = a2 * Ninv, Ex2 = a3 * Ninv, Eax = a4 * Ninv;
    double var1 = Ea2 - Ea * Ea;
    double g1 = bn1g[l * 128 + c], b1 = bn1b[l * 128 + c];
    double g2 = bn2g[l * 128 + c], b2v = bn2b[l * 128 + c];
    double s1d = g1 / sqrt(var1 + 1e-5);
    double t1 = b1 - Ea * s1d;
    double mu_o = s1d * Ea + t1 + Ex;
    double Eo2 = s1d * s1d * Ea2 + 2.0 * s1d * t1 * Ea + t1 * t1 + 2.0 * (s1d * Eax + t1 * Ex) + Ex2;
    double var_o = Eo2 - mu_o * mu_o;
    double s2d = g2 / sqrt(var_o + 1e-5);
    double t2 = b2v - mu_o * s2d;
    abc[c] = (float)(s1d * s2d);
    abc[128 + c] = (float)s2d;
    abc[256 + c] = (float)(t1 * s2d + t2);
  }
}

// ---------------- global mean pool + final MLP, last-layer BN fused inline ----------------
__global__ __launch_bounds__(512) void pool_mlp(const unsigned short* __restrict__ aggh,
                                                const unsigned short* __restrict__ xh,
                                                const float* __restrict__ abc,
                                                const float* __restrict__ W1,
                                                const float* __restrict__ b1,
                                                const float* __restrict__ W2,
                                                const float* __restrict__ b2,
                                                float* __restrict__ out) {
  __shared__ float red[512];
  __shared__ float gl[128];
  __shared__ float sABC[384];
  const int g = blockIdx.x, t = threadIdx.x;
  for (int u = t; u < 384; u += 512) sABC[u] = abc[u];
  __syncthreads();
  const int c = t & 127, q = t >> 7;
  const float A = sABC[c], B = sABC[128 + c], C = sABC[256 + c];
  const unsigned short* bagg = aggh + (size_t)g * NPG * EMBD;
  const unsigned short* bx = xh + (size_t)g * NPG * EMBD;
  float s = 0.f;
  for (int r = q; r < NPG; r += 4) {
    size_t idx = (size_t)r * EMBD + c;
    s += fmaxf(fmaf(A, bf2f(bagg[idx]), fmaf(B, bf2f(bx[idx]), C)), 0.f);
  }
  red[t] = s;
  __syncthreads();
  if (q == 0) gl[c] = (red[c] + red[128 + c] + red[256 + c] + red[384 + c]) * (1.f / NPG);
  __syncthreads();
  float acc = 0.f;
  for (int k = q * 32; k < q * 32 + 32; k++) acc = fmaf(gl[k], W1[k * EMBD + c], acc);
  red[t] = acc;
  __syncthreads();
  if (q == 0) {
    float h = fmaxf(red[c] + red[128 + c] + red[256 + c] + red[384 + c] + b1[c], 0.f);
    red[c] = h * W2[c];
  }
  __syncthreads();
  for (int sft = 64; sft > 0; sft >>= 1) {
    if (t < sft) red[t] += red[t + sft];
    __syncthreads();
  }
  if (t == 0) out[g] = red[0] + b2[0];
}

extern "C" void kernel_launch(void* const* d_in, const int* in_sizes, int n_in,
                              void* d_out, int out_size, void* d_ws, size_t ws_size,
                              hipStream_t stream) {
  const float* pos = (const float*)d_in[0];
  const float* emb = (const float*)d_in[1];
  const float* Wf = (const float*)d_in[2];
  const float* bf = (const float*)d_in[3];
  const float* Ws = (const float*)d_in[4];
  const float* bs = (const float*)d_in[5];
  const float* bn1g = (const float*)d_in[6];
  const float* bn1b = (const float*)d_in[7];
  const float* bn2g = (const float*)d_in[8];
  const float* bn2b = (const float*)d_in[9];
  const float* W1 = (const float*)d_in[10];
  const float* b1 = (const float*)d_in[11];
  const float* W2 = (const float*)d_in[12];
  const float* b2 = (const float*)d_in[13];
  const int* z = (const int*)d_in[14];
  const int* ei = (const int*)d_in[16];
  float* out = (float*)d_out;

  char* ws = (char*)d_ws;
  unsigned short* xhA = (unsigned short*)(ws + 0);           // 12,800,000
  unsigned short* xhB = (unsigned short*)(ws + 12800000);    // 12,800,000
  unsigned short* P = (unsigned short*)(ws + 25600000);      // 51,200,000
  unsigned short* aggh = (unsigned short*)(ws + 76800000);   // 12,800,000
  uint2* csr = (uint2*)(ws + 89600000);                      //  6,400,000
  int* deg = (int*)(ws + 96000000);                          //    200,000
  int* offs = (int*)(ws + 96200000);                         //    200,000
  unsigned short* whT = (unsigned short*)(ws + 96400000);    //    524,288
  float* partial = (float*)(ws + 96924288);                  //  2,560,000
  float* abc = (float*)(ws + 99484288);                      //      1,536

  unsigned short* xb[2] = {xhA, xhB};
  int cur = 0;

  prep_w<<<1024, 256, 0, stream>>>(Wf, Ws, whT);
  gather_x<<<2048, 256, 0, stream>>>(emb, z, xhA);
  csr_build<<<NG, 512, 0, stream>>>(ei, pos, offs, deg, csr);
  for (int l = 0; l < NL; l++) {
    gemm_proj<<<dim3(4, 391), 256, 0, stream>>>(xb[cur], aggh, abc, whT, P, xb[cur ^ 1], l);
    if (l > 0) cur ^= 1;  // xb[cur] now holds x_in(l)
    edge_gather<<<NN / 4, 256, 0, stream>>>(P, csr, offs, deg, Wf, bf, Ws, bs, aggh, l);
    col_stats<<<CS_BLOCKS, 256, 0, stream>>>(aggh, xb[cur], partial);
    bn_fold<<<8, 256, 0, stream>>>(partial, bn1g, bn1b, bn2g, bn2b, abc, l);
  }
  pool_mlp<<<NG, 512, 0, stream>>>(aggh, xb[cur], abc, W1, b1, W2, b2, out);
}

// Round 12
// 538.489 us; speedup vs baseline: 1.1491x; 1.0248x over previous
//
#include <hip/hip_runtime.h>

#define NN 50000
#define NG 100
#define NPG 500
#define NE 800000
#define EPG 8000
#define EMBD 128
#define NL 4
#define CS_BLOCKS 1000
#define CS_ROWS 50

typedef __attribute__((ext_vector_type(8))) short short8v;
typedef __attribute__((ext_vector_type(4))) float float4v;
typedef __attribute__((ext_vector_type(2))) float f2;

__device__ __forceinline__ unsigned short f2bf(float v) {
  unsigned u = __float_as_uint(v);
  u += 0x7FFFu + ((u >> 16) & 1u);
  return (unsigned short)(u >> 16);
}
__device__ __forceinline__ float bf2f(unsigned short h) {
  return __uint_as_float(((unsigned)h) << 16);
}

__device__ __forceinline__ float fexp2(float x) {
#if __has_builtin(__builtin_amdgcn_exp2f)
  return __builtin_amdgcn_exp2f(x);
#else
  float r; asm("v_exp_f32 %0, %1" : "=v"(r) : "v"(x)); return r;
#endif
}
__device__ __forceinline__ float flog2(float x) {
#if __has_builtin(__builtin_amdgcn_logf)
  return __builtin_amdgcn_logf(x);
#else
  float r; asm("v_log_f32 %0, %1" : "=v"(r) : "v"(x)); return r;
#endif
}
__device__ __forceinline__ float frcp(float x) {
#if __has_builtin(__builtin_amdgcn_rcpf)
  return __builtin_amdgcn_rcpf(x);
#else
  float r; asm("v_rcp_f32 %0, %1" : "=v"(r) : "v"(x)); return r;
#endif
}

__device__ __forceinline__ f2 unpk(unsigned v) {
  f2 r;
  r.x = __uint_as_float(v << 16);
  r.y = __uint_as_float(v & 0xffff0000u);
  return r;
}

// ---------------- fused setup: prep_w | gather_x | csr_build via block ranges ----------------
// blocks 0..511: whT prep (262144 elems); 512..1511: xh0=bf16(emb[z]); 1512..1611: CSR per graph
__global__ __launch_bounds__(512) void setup_all(const float* __restrict__ Wf,
                                                 const float* __restrict__ Ws,
                                                 unsigned short* __restrict__ whT,
                                                 const float* __restrict__ emb,
                                                 const int* __restrict__ z,
                                                 unsigned short* __restrict__ xh,
                                                 const int* __restrict__ ei,
                                                 const float* __restrict__ pos,
                                                 int* __restrict__ offs, int* __restrict__ deg,
                                                 uint2* __restrict__ csr) {
  __shared__ int s_hist[NPG];
  __shared__ int s_scan[512];
  const int b = blockIdx.x, t = threadIdx.x;
  if (b < 512) {
    // ---- prep_w: column-permuted Wcat^T layout ----
    // oc<128: i-f (Wf rows 0..127); 128<=oc<256: i-s (Ws rows 0..127);
    // oc>=256: j-interleaved t2=oc-256, p=t2>>2, r=t2&3, c=2p+(r&1), r<2->Wf else Ws, rows 128..255
    int idx = b * 512 + t;  // 4*512*128 = 262144
    int k = idx & 127;
    int oc = (idx >> 7) & 511;
    int l = idx >> 16;
    const float* W;
    int row, c;
    if (oc < 128) { W = Wf; row = k; c = oc; }
    else if (oc < 256) { W = Ws; row = k; c = oc - 128; }
    else {
      int t2 = oc - 256;
      int p = t2 >> 2, r = t2 & 3;
      c = 2 * p + (r & 1);
      W = (r < 2) ? Wf : Ws;
      row = 128 + k;
    }
    whT[idx] = f2bf(W[(size_t)l * 32896 + (size_t)row * 128 + c]);
  } else if (b < 1512) {
    // ---- gather_x ----
    const int total = NN * 32;
    for (int idx = (b - 512) * 512 + t; idx < total; idx += 1000 * 512) {
      int n = idx >> 5, c4 = (idx & 31) * 4;
      float4 v = *(const float4*)(emb + (size_t)z[n] * EMBD + c4);
      ushort4 h;
      h.x = f2bf(v.x); h.y = f2bf(v.y); h.z = f2bf(v.z); h.w = f2bf(v.w);
      *(ushort4*)(xh + (size_t)idx * 4) = h;
    }
  } else {
    // ---- csr_build: one block per graph ----
    const int g = b - 1512;
    const int nbase = g * NPG;
    const int e0 = g * EPG;
    for (int n = t; n < NPG; n += 512) s_hist[n] = 0;
    __syncthreads();
    for (int e = t; e < EPG; e += 512) atomicAdd(&s_hist[ei[NE + e0 + e] - nbase], 1);
    __syncthreads();
    int v = (t < NPG) ? s_hist[t] : 0;
    s_scan[t] = v;
    __syncthreads();
    for (int d = 1; d < 512; d <<= 1) {
      int a = (t >= d) ? s_scan[t - d] : 0;
      __syncthreads();
      s_scan[t] += a;
      __syncthreads();
    }
    if (t < NPG) {
      int off = s_scan[t] - v;
      offs[nbase + t] = e0 + off;
      deg[nbase + t] = v;
      s_hist[t] = off;
    }
    __syncthreads();
    for (int e = t; e < EPG; e += 512) {
      int j = ei[e0 + e];
      int i = ei[NE + e0 + e];
      float dx = pos[i * 3 + 0] - pos[j * 3 + 0];
      float dy = pos[i * 3 + 1] - pos[j * 3 + 1];
      float dz = pos[i * 3 + 2] - pos[j * 3 + 2];
      float dist = sqrtf(dx * dx + dy * dy + dz * dz);
      int p = atomicAdd(&s_hist[i - nbase], 1);
      csr[e0 + p] = make_uint2((unsigned)j, __float_as_uint(dist));
    }
  }
}

// ---------------- P[n][512] = x(bf16) @ Wcat (MFMA 16x16x32 bf16) ----------------
// grid = dim3(4, 391): col-block fastest so 4 consecutive blocks share the A-tile
#define BM 128
#define BN 128
__global__ __launch_bounds__(256, 2) void gemm_proj(const unsigned short* __restrict__ xh,
                                                    const unsigned short* __restrict__ whT,
                                                    unsigned short* __restrict__ P, int l) {
  __shared__ __align__(16) unsigned short smem[32768];  // 64 KB: sA | sB, then sC view
  unsigned short* sA = smem;
  unsigned short* sB = smem + 16384;
  const int tid = threadIdx.x;
  const int R0 = blockIdx.y * BM;
  const int C0 = blockIdx.x * BN;
  for (int gid = tid; gid < BM * 16; gid += 256) {
    int row = gid >> 4, gc = gid & 15;
    int grow = R0 + row;
    uint4 v = make_uint4(0u, 0u, 0u, 0u);
    if (grow < NN) v = *(const uint4*)(xh + (size_t)grow * 128 + gc * 8);
    int gs = (gc & 8) | ((gc ^ row) & 7);
    *(uint4*)((char*)sA + row * 256 + gs * 16) = v;
  }
  for (int gid = tid; gid < BN * 16; gid += 256) {
    int c = gid >> 4, gc = gid & 15;
    uint4 v = *(const uint4*)(whT + ((size_t)l * 512 + C0 + c) * 128 + gc * 8);
    int gs = (gc & 8) | ((gc ^ c) & 7);
    *(uint4*)((char*)sB + c * 256 + gs * 16) = v;
  }
  __syncthreads();
  const int w = tid >> 6, lane = tid & 63;
  const int lr = lane & 15, lk = lane >> 4;
  float4v acc[2][8];
#pragma unroll
  for (int i = 0; i < 2; i++)
#pragma unroll
    for (int j = 0; j < 8; j++) acc[i][j] = (float4v){0.f, 0.f, 0.f, 0.f};
#pragma unroll
  for (int kb = 0; kb < 4; kb++) {
    int g = kb * 4 + lk;
    short8v a[2], b[8];
#pragma unroll
    for (int rf = 0; rf < 2; rf++) {
      int row = w * 32 + rf * 16 + lr;
      int gs = (g & 8) | ((g ^ row) & 7);
      a[rf] = *(const short8v*)((const char*)sA + row * 256 + gs * 16);
    }
#pragma unroll
    for (int cf = 0; cf < 8; cf++) {
      int c = cf * 16 + lr;
      int gs = (g & 8) | ((g ^ c) & 7);
      b[cf] = *(const short8v*)((const char*)sB + c * 256 + gs * 16);
    }
#pragma unroll
    for (int rf = 0; rf < 2; rf++)
#pragma unroll
      for (int cf = 0; cf < 8; cf++)
        acc[rf][cf] = __builtin_amdgcn_mfma_f32_16x16x32_bf16(a[rf], b[cf], acc[rf][cf], 0, 0, 0);
  }
  __syncthreads();
  unsigned short* sC = smem;  // 128*136 shorts
#pragma unroll
  for (int rf = 0; rf < 2; rf++) {
#pragma unroll
    for (int cf = 0; cf < 8; cf++) {
      int col = cf * 16 + lr;
#pragma unroll
      for (int j = 0; j < 4; j++) {
        int row = w * 32 + rf * 16 + lk * 4 + j;
        sC[row * 136 + col] = f2bf(acc[rf][cf][j]);
      }
    }
  }
  __syncthreads();
  for (int it = tid; it < BM * 16; it += 256) {
    int row = it >> 4, gc = it & 15;
    int grow = R0 + row;
    if (grow < NN) {
      uint4 v = *(const uint4*)(sC + row * 136 + gc * 8);
      *(uint4*)(P + (size_t)grow * 512 + C0 + gc * 8) = v;
    }
  }
}

// ---------------- edge gather: one wave per dst node, simple 4-unroll + XCD swizzle ----------------
__global__ __launch_bounds__(256) void edge_gather(const unsigned short* __restrict__ P,
                                                   const uint2* __restrict__ csr,
                                                   const int* __restrict__ offs,
                                                   const int* __restrict__ deg,
                                                   const float* __restrict__ Wf,
                                                   const float* __restrict__ bf,
                                                   const float* __restrict__ Ws,
                                                   const float* __restrict__ bs,
                                                   unsigned short* __restrict__ aggh, int l) {
  const float L = 1.4426950408889634f;   // log2(e)
  const float LN2 = 0.6931471805599453f;
  const int lane = threadIdx.x & 63;
  const int wid = __builtin_amdgcn_readfirstlane(threadIdx.x >> 6);
  // bijective XCD-chunked swizzle: nwg = 12500, q = 1562, r = 4
  const int bid = blockIdx.x;
  const int xcd = bid & 7, bidx = bid >> 3;
  const int wg = (xcd < 4) ? xcd * 1563 + bidx : 4 * 1563 + (xcd - 4) * 1562 + bidx;
  const int i = wg * 4 + wid;
  const int f0 = lane * 2;

  const unsigned* Piu = (const unsigned*)(P + (size_t)i * 512);
  unsigned pif = Piu[lane];       // i-f (cols 0..127)
  unsigned pis = Piu[64 + lane];  // i-s (cols 128..255)

  float2 wfd = *(const float2*)(Wf + (size_t)l * 32896 + 256 * 128 + f0);
  float2 wsd = *(const float2*)(Ws + (size_t)l * 32896 + 256 * 128 + f0);
  float2 bfv = *(const float2*)(bf + l * 128 + f0);
  float2 bsv = *(const float2*)(bs + l * 128 + f0);

  f2 bflv, bslv, wflv, wslv;
  {
    f2 pi_f = unpk(pif), pi_s = unpk(pis);
    bflv.x = (pi_f.x + bfv.x) * L; bflv.y = (pi_f.y + bfv.y) * L;
    bslv.x = (pi_s.x + bsv.x) * L; bslv.y = (pi_s.y + bsv.y) * L;
    wflv.x = wfd.x * L; wflv.y = wfd.y * L;
    wslv.x = wsd.x * L; wslv.y = wsd.y * L;
  }

  const int off = __builtin_amdgcn_readfirstlane(offs[i]);
  const int nd = __builtin_amdgcn_readfirstlane(deg[i]);
  const uint2* ep = csr + off;
  f2 acc = (f2){0.f, 0.f};

// dv is wave-uniform but only feeds vector math -> use directly, no readfirstlane
#define EDGE_BODY(DVU, V)                                          \
  {                                                                \
    float dv = __uint_as_float(DVU);                               \
    f2 pf = unpk((V).x) * L + (bflv + dv * wflv);                  \
    f2 ps = unpk((V).y) * L + (bslv + dv * wslv);                  \
    f2 a, b, r, lg;                                                \
    a.x = fexp2(-pf.x); a.y = fexp2(-pf.y);                        \
    b.x = fexp2(ps.x);  b.y = fexp2(ps.y);                         \
    r.x = frcp(a.x + 1.f); r.y = frcp(a.y + 1.f);                  \
    lg.x = flog2(b.x + 1.f); lg.y = flog2(b.y + 1.f);              \
    acc += r * lg;                                                 \
  }

  int k = 0;
  for (; k + 3 < nd; k += 4) {
    uint2 e0 = ep[k], e1 = ep[k + 1], e2 = ep[k + 2], e3 = ep[k + 3];
    unsigned j0 = __builtin_amdgcn_readfirstlane(e0.x);
    unsigned j1 = __builtin_amdgcn_readfirstlane(e1.x);
    unsigned j2 = __builtin_amdgcn_readfirstlane(e2.x);
    unsigned j3 = __builtin_amdgcn_readfirstlane(e3.x);
    uint2 v0 = ((const uint2*)(P + (size_t)j0 * 512))[64 + lane];
    uint2 v1 = ((const uint2*)(P + (size_t)j1 * 512))[64 + lane];
    uint2 v2 = ((const uint2*)(P + (size_t)j2 * 512))[64 + lane];
    uint2 v3 = ((const uint2*)(P + (size_t)j3 * 512))[64 + lane];
    EDGE_BODY(e0.y, v0)
    EDGE_BODY(e1.y, v1)
    EDGE_BODY(e2.y, v2)
    EDGE_BODY(e3.y, v3)
  }
  for (; k < nd; k++) {
    uint2 e0 = ep[k];
    unsigned j0 = __builtin_amdgcn_readfirstlane(e0.x);
    uint2 v0 = ((const uint2*)(P + (size_t)j0 * 512))[64 + lane];
    EDGE_BODY(e0.y, v0)
  }
#undef EDGE_BODY

  acc.x *= LN2; acc.y *= LN2;
  unsigned packed = ((unsigned)f2bf(acc.y) << 16) | (unsigned)f2bf(acc.x);
  ((unsigned*)(aggh + (size_t)i * EMBD))[lane] = packed;
}

// ---------------- col stats: agg bf16 + x bf16 ----------------
__global__ __launch_bounds__(256) void col_stats(const unsigned short* __restrict__ aggh,
                                                 const unsigned short* __restrict__ xh,
                                                 float* __restrict__ partial) {
  const int b = blockIdx.x, tid = threadIdx.x;
  const int c4 = tid & 31;
  const int h = tid >> 5;
  const int r0 = b * CS_ROWS;
  float4 sa = {0, 0, 0, 0}, sa2 = {0, 0, 0, 0}, sx = {0, 0, 0, 0}, sx2 = {0, 0, 0, 0},
         sax = {0, 0, 0, 0};
  for (int rr = h; rr < CS_ROWS; rr += 8) {
    size_t idx = (size_t)(r0 + rr) * EMBD + c4 * 4;
    ushort4 ha = *(const ushort4*)(aggh + idx);
    ushort4 hx = *(const ushort4*)(xh + idx);
    float a0 = bf2f(ha.x), a1 = bf2f(ha.y), a2 = bf2f(ha.z), a3 = bf2f(ha.w);
    float x0 = bf2f(hx.x), x1 = bf2f(hx.y), x2 = bf2f(hx.z), x3 = bf2f(hx.w);
    sa.x += a0; sa.y += a1; sa.z += a2; sa.w += a3;
    sa2.x += a0 * a0; sa2.y += a1 * a1; sa2.z += a2 * a2; sa2.w += a3 * a3;
    sx.x += x0; sx.y += x1; sx.z += x2; sx.w += x3;
    sx2.x += x0 * x0; sx2.y += x1 * x1; sx2.z += x2 * x2; sx2.w += x3 * x3;
    sax.x += a0 * x0; sax.y += a1 * x1; sax.z += a2 * x2; sax.w += a3 * x3;
  }
  __shared__ float4 sm[256];
  float* p = partial + (size_t)b * 640;
#define REDUCE_STAT(V, OUTOFF)                                              \
  sm[tid] = V;                                                              \
  __syncthreads();                                                          \
  if (h == 0) {                                                             \
    float4 s = sm[tid];                                                     \
    for (int g = 1; g < 8; g++) {                                           \
      float4 o = sm[g * 32 + tid];                                          \
      s.x += o.x; s.y += o.y; s.z += o.z; s.w += o.w;                       \
    }                                                                       \
    *(float4*)(p + (OUTOFF) + c4 * 4) = s;                                  \
  }                                                                         \
  __syncthreads();
  REDUCE_STAT(sa, 0)
  REDUCE_STAT(sa2, 128)
  REDUCE_STAT(sx, 256)
  REDUCE_STAT(sx2, 384)
  REDUCE_STAT(sax, 512)
#undef REDUCE_STAT
}

// ---------------- fold: partial[1000][640] -> BN coeffs, 8 blocks x 16 cols ----------------
__global__ __launch_bounds__(256) void bn_fold(const float* __restrict__ partial,
                                               const float* __restrict__ bn1g,
                                               const float* __restrict__ bn1b,
                                               const float* __restrict__ bn2g,
                                               const float* __restrict__ bn2b,
                                               float* __restrict__ abc, int l) {
  __shared__ float sm[5 * 256];
  const int t = threadIdx.x;
  const int ci = t & 15;
  const int col = blockIdx.x * 16 + ci;
  const int chunk = t >> 4;
  float s0 = 0, s1 = 0, s2 = 0, s3 = 0, s4 = 0;
  for (int b = chunk; b < CS_BLOCKS; b += 16) {
    const float* p = partial + (size_t)b * 640 + col;
    s0 += p[0]; s1 += p[128]; s2 += p[256]; s3 += p[384]; s4 += p[512];
  }
  sm[t] = s0; sm[256 + t] = s1; sm[512 + t] = s2; sm[768 + t] = s3; sm[1024 + t] = s4;
  __syncthreads();
  if (t < 16) {
    int c = blockIdx.x * 16 + t;
    float a0 = 0, a1 = 0, a2 = 0, a3 = 0, a4 = 0;
    for (int ch = 0; ch < 16; ch++) {
      int u = ch * 16 + t;
      a0 += sm[u]; a1 += sm[256 + u]; a2 += sm[512 + u]; a3 += sm[768 + u]; a4 += sm[1024 + u];
    }
    const double Ninv = 1.0 / (double)NN;
    double Ea = a0 * Ninv, Ea2 = a1 * Ninv, Ex = a2 * Ninv, Ex2 = a3 * Ninv, Eax = a4 * Ninv;
    double var1 = Ea2 - Ea * Ea;
    double g1 = bn1g[l * 128 + c], b1 = bn1b[l * 128 + c];
    double g2 = bn2g[l * 128 + c], b2v = bn2b[l * 128 + c];
    double s1d = g1 / sqrt(var1 + 1e-5);
    double t1 = b1 - Ea * s1d;
    double mu_o = s1d * Ea + t1 + Ex;
    double Eo2 = s1d * s1d * Ea2 + 2.0 * s1d * t1 * Ea + t1 * t1 + 2.0 * (s1d * Eax + t1 * Ex) + Ex2;
    double var_o = Eo2 - mu_o * mu_o;
    double s2d = g2 / sqrt(var_o + 1e-5);
    double t2 = b2v - mu_o * s2d;
    abc[c] = (float)(s1d * s2d);
    abc[128 + c] = (float)s2d;
    abc[256 + c] = (float)(t1 * s2d + t2);
  }
}

// ---------------- xh = bf16(relu(A*agg + B*x + C)), in place ----------------
__global__ void fuse_bn(const unsigned short* __restrict__ aggh, unsigned short* __restrict__ xh,
                        const float* __restrict__ abc) {
  const int total = NN * 32;
  for (int idx = blockIdx.x * 256 + threadIdx.x; idx < total; idx += gridDim.x * 256) {
    int c4 = (idx & 31) * 4;
    size_t base = (size_t)idx * 4;
    ushort4 ha = *(const ushort4*)(aggh + base);
    ushort4 hx = *(const ushort4*)(xh + base);
    float4 A = *(const float4*)(abc + c4);
    float4 B = *(const float4*)(abc + 128 + c4);
    float4 C = *(const float4*)(abc + 256 + c4);
    float4 o;
    o.x = fmaxf(fmaf(A.x, bf2f(ha.x), fmaf(B.x, bf2f(hx.x), C.x)), 0.f);
    o.y = fmaxf(fmaf(A.y, bf2f(ha.y), fmaf(B.y, bf2f(hx.y), C.y)), 0.f);
    o.z = fmaxf(fmaf(A.z, bf2f(ha.z), fmaf(B.z, bf2f(hx.z), C.z)), 0.f);
    o.w = fmaxf(fmaf(A.w, bf2f(ha.w), fmaf(B.w, bf2f(hx.w), C.w)), 0.f);
    ushort4 hh;
    hh.x = f2bf(o.x); hh.y = f2bf(o.y); hh.z = f2bf(o.z); hh.w = f2bf(o.w);
    *(ushort4*)(xh + base) = hh;
  }
}

// ---------------- global mean pool + final MLP (merged) ----------------
__global__ __launch_bounds__(512) void pool_mlp(const unsigned short* __restrict__ xh,
                                                const float* __restrict__ W1,
                                                const float* __restrict__ b1,
                                                const float* __restrict__ W2,
                                                const float* __restrict__ b2,
                                                float* __restrict__ out) {
  __shared__ float red[512];
  __shared__ float gl[128];
  const int g = blockIdx.x, t = threadIdx.x;
  const int c = t & 127, q = t >> 7;
  const unsigned short* bx = xh + (size_t)g * NPG * EMBD;
  float s = 0.f;
  for (int r = q; r < NPG; r += 4) s += bf2f(bx[(size_t)r * EMBD + c]);
  red[t] = s;
  __syncthreads();
  if (q == 0) gl[c] = (red[c] + red[128 + c] + red[256 + c] + red[384 + c]) * (1.f / NPG);
  __syncthreads();
  float acc = 0.f;
  for (int k = q * 32; k < q * 32 + 32; k++) acc = fmaf(gl[k], W1[k * EMBD + c], acc);
  red[t] = acc;
  __syncthreads();
  if (q == 0) {
    float h = fmaxf(red[c] + red[128 + c] + red[256 + c] + red[384 + c] + b1[c], 0.f);
    red[c] = h * W2[c];
  }
  __syncthreads();
  for (int sft = 64; sft > 0; sft >>= 1) {
    if (t < sft) red[t] += red[t + sft];
    __syncthreads();
  }
  if (t == 0) out[g] = red[0] + b2[0];
}

extern "C" void kernel_launch(void* const* d_in, const int* in_sizes, int n_in,
                              void* d_out, int out_size, void* d_ws, size_t ws_size,
                              hipStream_t stream) {
  const float* pos = (const float*)d_in[0];
  const float* emb = (const float*)d_in[1];
  const float* Wf = (const float*)d_in[2];
  const float* bf = (const float*)d_in[3];
  const float* Ws = (const float*)d_in[4];
  const float* bs = (const float*)d_in[5];
  const float* bn1g = (const float*)d_in[6];
  const float* bn1b = (const float*)d_in[7];
  const float* bn2g = (const float*)d_in[8];
  const float* bn2b = (const float*)d_in[9];
  const float* W1 = (const float*)d_in[10];
  const float* b1 = (const float*)d_in[11];
  const float* W2 = (const float*)d_in[12];
  const float* b2 = (const float*)d_in[13];
  const int* z = (const int*)d_in[14];
  const int* ei = (const int*)d_in[16];
  float* out = (float*)d_out;

  char* ws = (char*)d_ws;
  unsigned short* xh = (unsigned short*)(ws + 0);            // 12,800,000
  unsigned short* P = (unsigned short*)(ws + 12800000);      // 51,200,000
  unsigned short* aggh = (unsigned short*)(ws + 64000000);   // 12,800,000
  uint2* csr = (uint2*)(ws + 76800000);                      //  6,400,000
  int* deg = (int*)(ws + 83200000);                          //    200,000
  int* offs = (int*)(ws + 83400000);                         //    200,000
  unsigned short* whT = (unsigned short*)(ws + 83600000);    //    524,288
  float* partial = (float*)(ws + 84124288);                  //  2,560,000
  float* abc = (float*)(ws + 86684288);                      //      1,536

  setup_all<<<1612, 512, 0, stream>>>(Wf, Ws, whT, emb, z, xh, ei, pos, offs, deg, csr);
  for (int l = 0; l < NL; l++) {
    gemm_proj<<<dim3(4, 391), 256, 0, stream>>>(xh, whT, P, l);
    edge_gather<<<NN / 4, 256, 0, stream>>>(P, csr, offs, deg, Wf, bf, Ws, bs, aggh, l);
    col_stats<<<CS_BLOCKS, 256, 0, stream>>>(aggh, xh, partial);
    bn_fold<<<8, 256, 0, stream>>>(partial, bn1g, bn1b, bn2g, bn2b, abc, l);
    fuse_bn<<<2048, 256, 0, stream>>>(aggh, xh, abc);
  }
  pool_mlp<<<NG, 512, 0, stream>>>(xh, W1, b1, W2, b2, out);
}